// Round 13
// baseline (18.710 us; speedup 1.0000x reference)
//
#include <hip/hip_runtime.h>
#include <math.h>

#define S_ 32
#define B_ 128
#define M_ 128
#define F_ 512
#define C_ 100

typedef _Float16 f16;
typedef _Float16 f16x8 __attribute__((ext_vector_type(8)));
typedef float f32x4 __attribute__((ext_vector_type(4)));

// One kernel. Grid (4 mq, 128 b) = 512 blocks (2/CU), 512 thr = 8 waves.
// Each block: full base+softmax (redundant x4 per b, cheap) + D for its 32-m slice.
// Phase D waves: (pt, mt, kh) = output tile (16p x 16m) x K-half; LDS exchange.
__global__ __launch_bounds__(512) void k_all(
    const float* __restrict__ x, const int* __restrict__ y,
    const float* __restrict__ Z, const float* __restrict__ alpha0,
    const float* __restrict__ alpha, const float* __restrict__ beta0,
    const float* __restrict__ beta, float* __restrict__ out) {
  const int mq = blockIdx.x;   // 0..3 (32-m slice)
  const int b = blockIdx.y;    // 0..127
  const int tid = threadIdx.x;
  const int lane = tid & 63;
  const int w = tid >> 6;      // 0..7
  const int l15 = lane & 15;
  const int lg = lane >> 4;    // 0..3

  // Fragment blobs: slot = frag_id*64 + lane, 8 f16 (16B) per slot.
  __shared__ __align__(16) f16 ZAf[512 * 8];    // 8 KB Z frags (kc,rt); A-op of B; signs
  __shared__ __align__(16) f16 PtAf[512 * 8];   // 8 KB P frags (kc,pt); A-op of D
  __shared__ float baseS[S_ * 112];             // 14 KB
  __shared__ __align__(16) float pnS[4 * 2 * 64 * 4];  // 8 KB D-partials (tile,sign,lane,j)
  __shared__ float PybS[S_];
  __shared__ float etaS[32];
  __shared__ float redS[64];

  const int yb = y[b];

  // ---- A1: Z -> ZAf fragment slots (thread == slot; conflict-free) ----
  {
    int s = tid;
    int kcs = s >> 7, rts = (s >> 6) & 1;
    int lgs = (s >> 4) & 3, l15s = s & 15;
    int p = rts * 16 + l15s;
    int m0 = kcs * 32 + lgs * 8;
    const float* zrow = Z + ((size_t)p * B_ + b) * M_ + m0;
    float4 u0 = *(const float4*)zrow;
    float4 u1 = *(const float4*)(zrow + 4);
    f16x8 hv = {(f16)u0.x, (f16)u0.y, (f16)u0.z, (f16)u0.w,
                (f16)u1.x, (f16)u1.y, (f16)u1.z, (f16)u1.w};
    *(f16x8*)&ZAf[s * 8] = hv;
  }

  // ---- A2: eta for this 32-m slice; wave w -> m_local = w*4 + lg ----
  {
    const float4* x4 = (const float4*)x;
    const float4* a4 = (const float4*)alpha;
    float4 xr[8];
#pragma unroll
    for (int r = 0; r < 8; ++r) xr[r] = x4[b * 128 + r * 16 + l15];
    int ml = w * 4 + lg;
    int m = mq * 32 + ml;
    float acc = 0.f;
#pragma unroll
    for (int r = 0; r < 8; ++r) {
      float4 av = a4[(size_t)m * 128 + r * 16 + l15];
      float4 xv = xr[r];
      acc = fmaf(av.x, xv.x, acc); acc = fmaf(av.y, xv.y, acc);
      acc = fmaf(av.z, xv.z, acc); acc = fmaf(av.w, xv.w, acc);
    }
    acc += __shfl_xor(acc, 1);
    acc += __shfl_xor(acc, 2);
    acc += __shfl_xor(acc, 4);
    acc += __shfl_xor(acc, 8);
    if (l15 == 0) {
      float l = alpha0[m] + acc;
      etaS[ml] = 1.f / (1.f + __expf(-l));
    }
  }

  // ---- A3: phase-B B-frags from global beta rows (w<7) ----
  const int colB = w * 16 + l15;
  f16x8 bfr[4];
  if (w < 7) {
    const float* brow = beta + (size_t)((colB < C_) ? colB : C_ - 1) * M_;
    bool ok = colB < C_;
#pragma unroll
    for (int kc = 0; kc < 4; ++kc) {
      int m0 = kc * 32 + lg * 8;
      float4 u0 = *(const float4*)(brow + m0);
      float4 u1 = *(const float4*)(brow + m0 + 4);
      if (!ok) { u0 = make_float4(0,0,0,0); u1 = make_float4(0,0,0,0); }
      bfr[kc] = (f16x8){(f16)u0.x, (f16)u0.y, (f16)u0.z, (f16)u0.w,
                        (f16)u1.x, (f16)u1.y, (f16)u1.z, (f16)u1.w};
    }
  }

  // ---- A4: phase-D B-frags (K-half kh only): exp(+/-2*beta[c][m]) ----
  const int pt = (w >> 2) & 1, mt = (w >> 1) & 1, kh = w & 1;
  const int mD = mq * 32 + mt * 16 + l15;
  f16x8 bp[2], bn[2];
  {
    const float* bcol = beta + mD;
#pragma unroll
    for (int t = 0; t < 2; ++t) {
      int kc = kh * 2 + t;
      f16x8 ep, en;
#pragma unroll
      for (int ii = 0; ii < 8; ++ii) {
        int c = kc * 32 + lg * 8 + ii;
        int cs = (c < C_) ? c : C_ - 1;   // clamped; P=0 there
        float bv = bcol[(size_t)cs * M_];
        float e = __expf(2.f * bv);
        ep[ii] = (f16)e;
        en[ii] = (f16)(1.f / e);
      }
      bp[t] = ep;
      bn[t] = en;
    }
  }
  __syncthreads();  // (1) ZAf, etaS ready

  // ---- B: base[32 p][112 c] = Z x beta^T (K=128) ----
  if (w < 7) {
    f32x4 acc0 = {0.f, 0.f, 0.f, 0.f}, acc1 = {0.f, 0.f, 0.f, 0.f};
#pragma unroll
    for (int kc = 0; kc < 4; ++kc) {
      f16x8 a0 = *(const f16x8*)&ZAf[((kc * 2 + 0) * 64 + lane) * 8];
      f16x8 a1 = *(const f16x8*)&ZAf[((kc * 2 + 1) * 64 + lane) * 8];
      acc0 = __builtin_amdgcn_mfma_f32_16x16x32_f16(a0, bfr[kc], acc0, 0, 0, 0);
      acc1 = __builtin_amdgcn_mfma_f32_16x16x32_f16(a1, bfr[kc], acc1, 0, 0, 0);
    }
    float b0v = (colB < C_) ? beta0[colB] : 0.f;
#pragma unroll
    for (int j = 0; j < 4; ++j) {
      baseS[(lg * 4 + j) * 112 + colB] = acc0[j] + b0v;
      baseS[(16 + lg * 4 + j) * 112 + colB] = acc1[j] + b0v;
    }
  }
  __syncthreads();  // (2) base ready

  // ---- C: softmax; wave w -> rows p = 4w..4w+3 -> PtAf frag slots ----
  {
#pragma unroll
    for (int k = 0; k < 4; ++k) {
      int p = w * 4 + k;
      float v1 = baseS[p * 112 + lane];
      float v2 = (lane < 36) ? baseS[p * 112 + 64 + lane] : -1e30f;
      float mx = fmaxf(v1, v2);
#pragma unroll
      for (int off = 32; off > 0; off >>= 1) mx = fmaxf(mx, __shfl_xor(mx, off));
      float e1 = __expf(v1 - mx);
      float e2 = (lane < 36) ? __expf(v2 - mx) : 0.f;
      float sm = e1 + e2;
#pragma unroll
      for (int off = 32; off > 0; off >>= 1) sm += __shfl_xor(sm, off);
      float rd = 1.f / sm;
      float p1 = e1 * rd;
      float p2 = (lane < 36) ? e2 * rd : 0.f;
      int ptp = p >> 4, l15p = p & 15;
      {
        int c = lane, kc = c >> 5, lg2 = (c >> 3) & 3, ii = c & 7;
        PtAf[((kc * 2 + ptp) * 64 + lg2 * 16 + l15p) * 8 + ii] = (f16)p1;
      }
      {
        int c = lane + 64, kc = c >> 5, lg2 = (c >> 3) & 3, ii = c & 7;
        PtAf[((kc * 2 + ptp) * 64 + lg2 * 16 + l15p) * 8 + ii] = (f16)p2;
      }
      if (lane == yb) PybS[p] = p1;
      if (lane + 64 == yb) PybS[p] = p2;
    }
  }
  __syncthreads();  // (3) PtAf, PybS ready

  // ---- D: tile (pt, mt), K-half kh: 2+2 MFMA; exchange K-halves in LDS ----
  f32x4 pA = {0.f, 0.f, 0.f, 0.f}, nA = {0.f, 0.f, 0.f, 0.f};
#pragma unroll
  for (int t = 0; t < 2; ++t) {
    int kc = kh * 2 + t;
    f16x8 a0 = *(const f16x8*)&PtAf[((kc * 2 + pt) * 64 + lane) * 8];
    pA = __builtin_amdgcn_mfma_f32_16x16x32_f16(a0, bp[t], pA, 0, 0, 0);
    nA = __builtin_amdgcn_mfma_f32_16x16x32_f16(a0, bn[t], nA, 0, 0, 0);
  }
  {
    int tile = pt * 2 + mt;
    if (kh == 1) {
      *(f32x4*)&pnS[((tile * 2 + 0) * 64 + lane) * 4] = pA;
      *(f32x4*)&pnS[((tile * 2 + 1) * 64 + lane) * 4] = nA;
    }
  }
  __syncthreads();  // (4) partner partials visible

  if (kh == 0) {
    int tile = pt * 2 + mt;
    f32x4 pB = *(const f32x4*)&pnS[((tile * 2 + 0) * 64 + lane) * 4];
    f32x4 nB = *(const f32x4*)&pnS[((tile * 2 + 1) * 64 + lane) * 4];
#pragma unroll
    for (int j = 0; j < 4; ++j) { pA[j] += pB[j]; nA[j] += nB[j]; }

    int m = mD;
    float bym = beta[yb * M_ + m];
    float epy = __expf(2.f * bym), eny = 1.f / epy;
    float eta_v = etaS[mt * 16 + l15];
    float ome = 1.f - eta_v;
    float o = 0.f;
    int kcz = m >> 5, lgz = (m >> 3) & 3, iiz = m & 7;
#pragma unroll
    for (int j = 0; j < 4; ++j) {
      int p = pt * 16 + lg * 4 + j;
      float z = (float)ZAf[((kcz * 2 + (p >> 4)) * 64 + lgz * 16 + (p & 15)) * 8 + iiz];
      float pyb = PybS[p];
      o += (z > 0.f) ? fmaf(pyb, eta_v, (pyb * eny / nA[j]) * ome)
                     : fmaf(pyb * epy / pA[j], eta_v, pyb * ome);
    }
    o += __shfl_xor(o, 16);
    o += __shfl_xor(o, 32);
    if (lane < 16) redS[pt * 32 + mt * 16 + l15] = o;
  }
  __syncthreads();  // (5)

  if (tid < 32) out[b * M_ + mq * 32 + tid] = redS[tid] + redS[32 + tid];
}

extern "C" void kernel_launch(void* const* d_in, const int* in_sizes, int n_in,
                              void* d_out, int out_size, void* d_ws, size_t ws_size,
                              hipStream_t stream) {
  const float* x = (const float*)d_in[0];
  const int* y = (const int*)d_in[1];
  const float* Z = (const float*)d_in[2];
  const float* alpha0 = (const float*)d_in[3];
  const float* alpha = (const float*)d_in[4];
  const float* beta0 = (const float*)d_in[5];
  const float* beta = (const float*)d_in[6];
  float* out = (float*)d_out;

  k_all<<<dim3(4, B_), dim3(512), 0, stream>>>(x, y, Z, alpha0, alpha, beta0,
                                               beta, out);
}

// Round 14
// 15.468 us; speedup vs baseline: 1.2095x; 1.2095x over previous
//
#include <hip/hip_runtime.h>
#include <math.h>

#define S_ 32
#define B_ 128
#define M_ 128
#define F_ 512
#define C_ 100
#define SB 8      // s-rows per k_main block

typedef _Float16 f16;
typedef _Float16 f16x8 __attribute__((ext_vector_type(8)));
typedef float f32x4 __attribute__((ext_vector_type(4)));

// ws layout (bytes):
//  BTf  @ 0     : 4 kc x 7 ct x 64 lane x 16B = 28672   beta frags   [B-op, phase B]
//  EPf  @ 28672 : 4 kc x 8 mt x 64 lane x 16B = 32768   exp(+2*beta) [B-op, phase D]
//  ENf  @ 61440 : 32768                                 exp(-2*beta)
//  etag @ 94208 : f32[128][128] = 65536
#define WS_BT  0
#define WS_EP  28672
#define WS_EN  61440
#define WS_ETA 94208

// ---- k_pre: blocks 0..255 -> eta (b, m-half) + zero out; 256..267 -> tables ----
__global__ __launch_bounds__(512) void k_pre(
    const float* __restrict__ x, const float* __restrict__ alpha0,
    const float* __restrict__ alpha, const float* __restrict__ beta,
    char* __restrict__ ws, float* __restrict__ out) {
  const int bid = blockIdx.x;
  const int tid = threadIdx.x;
  __shared__ float betaS[C_ * M_];  // used by table blocks only
  if (bid < 256) {
    const int b = bid >> 1, mh = bid & 1;
    float* etag = (float*)(ws + WS_ETA);
    const int lane = tid & 63, w = tid >> 6, l15 = lane & 15, lg = lane >> 4;
    if (tid < 64) out[b * M_ + mh * 64 + tid] = 0.f;
    const float4* x4 = (const float4*)x;
    const float4* a4 = (const float4*)alpha;
    float4 xr[8];
#pragma unroll
    for (int r = 0; r < 8; ++r) xr[r] = x4[b * 128 + r * 16 + l15];
#pragma unroll
    for (int j = 0; j < 2; ++j) {
      int m = mh * 64 + w * 8 + j * 4 + lg;
      float acc = 0.f;
#pragma unroll
      for (int r = 0; r < 8; ++r) {
        float4 av = a4[(size_t)m * 128 + r * 16 + l15];
        float4 xv = xr[r];
        acc = fmaf(av.x, xv.x, acc); acc = fmaf(av.y, xv.y, acc);
        acc = fmaf(av.z, xv.z, acc); acc = fmaf(av.w, xv.w, acc);
      }
      acc += __shfl_xor(acc, 1);
      acc += __shfl_xor(acc, 2);
      acc += __shfl_xor(acc, 4);
      acc += __shfl_xor(acc, 8);
      if (l15 == 0) {
        float l = alpha0[m] + acc;
        etag[b * 128 + m] = 1.f / (1.f + __expf(-l));
      }
    }
  } else {
    for (int i = tid; i < C_ * M_; i += 512) betaS[i] = beta[i];
    __syncthreads();
    const int ci = (bid - 256) * 512 + tid;  // 0..6143; active < 5888
    if (ci < 1792) {                         // BTf frag(kc,ct): beta[c][m-seg]
      int lane = ci & 63, t = ci >> 6;
      int ct = t % 7, kc = t / 7;
      int c = ct * 16 + (lane & 15);
      int m0 = kc * 32 + (lane >> 4) * 8;
      f16x8 v;
#pragma unroll
      for (int i = 0; i < 8; ++i)
        v[i] = (c < C_) ? (f16)betaS[c * M_ + m0 + i] : (f16)0.f;
      *(f16x8*)(ws + WS_BT + (size_t)ci * 16) = v;
    } else if (ci < 3840) {                  // EPf frag(kc,mt): exp(+2*beta[c-seg][m])
      int q = ci - 1792;
      int lane = q & 63, t = q >> 6;
      int m = (t & 7) * 16 + (lane & 15);
      int c0 = (t >> 3) * 32 + (lane >> 4) * 8;
      f16x8 v;
#pragma unroll
      for (int i = 0; i < 8; ++i) {
        int c = c0 + i;
        v[i] = (c < C_) ? (f16)__expf(2.f * betaS[c * M_ + m]) : (f16)0.f;
      }
      *(f16x8*)(ws + WS_EP + (size_t)q * 16) = v;
    } else if (ci < 5888) {                  // ENf
      int q = ci - 3840;
      int lane = q & 63, t = q >> 6;
      int m = (t & 7) * 16 + (lane & 15);
      int c0 = (t >> 3) * 32 + (lane >> 4) * 8;
      f16x8 v;
#pragma unroll
      for (int i = 0; i < 8; ++i) {
        int c = c0 + i;
        v[i] = (c < C_) ? (f16)__expf(-2.f * betaS[c * M_ + m]) : (f16)0.f;
      }
      *(f16x8*)(ws + WS_EN + (size_t)q * 16) = v;
    }
  }
}

// ---- k_main: grid (4 sh, 128 b) = 512 blocks, 512 thr = 8 waves; SB=8 ----
__global__ __launch_bounds__(512) void k_main(
    const int* __restrict__ y, const float* __restrict__ Z,
    const float* __restrict__ beta0, const float* __restrict__ beta,
    const char* __restrict__ ws, float* __restrict__ out) {
  const int sh = blockIdx.x;   // 0..3
  const int b = blockIdx.y;    // 0..127
  const int tid = threadIdx.x;
  const int lane = tid & 63;
  const int w = tid >> 6;      // 0..7
  const int l15 = lane & 15;
  const int lg = lane >> 4;    // 0..3
  const int s0 = sh * SB;

  // Fragment blobs (slot = frag*64+lane, 16B/slot) -> conflict-free b128
  __shared__ __align__(16) f16 ZAf[256 * 8];    // 4 KB: Z frags (4 kc), rows 8..15 zero
  __shared__ __align__(16) f16 PtAf[256 * 8];   // 4 KB: P frags (4 kc), rows 8..15 zero
  __shared__ float baseS[SB * 112];             // 3.5 KB
  __shared__ float PybS[SB];

  const int yb = y[b];
  const int m = w * 16 + l15;  // this thread's m in phases D/epilogue (m-tile w)

  // ---- A: stage Z frags (tid<256); issue-early everything else ----
  if (tid < 256) {
    int s = tid;
    int kcs = s >> 6, lgs = (s >> 4) & 3, l15s = s & 15;
    f16x8 hv = {0, 0, 0, 0, 0, 0, 0, 0};
    if (l15s < SB) {
      const float* zrow = Z + ((size_t)(s0 + l15s) * B_ + b) * M_ + kcs * 32 + lgs * 8;
      float4 u0 = *(const float4*)zrow;
      float4 u1 = *(const float4*)(zrow + 4);
      hv = (f16x8){(f16)u0.x, (f16)u0.y, (f16)u0.z, (f16)u0.w,
                   (f16)u1.x, (f16)u1.y, (f16)u1.z, (f16)u1.w};
    }
    *(f16x8*)&ZAf[s * 8] = hv;
  }

  // Issue-early: phase-B frags (w<7), phase-D frags (mt=w), epilogue scalars
  f16x8 bfr[4], bp[4], bn[4];
#pragma unroll
  for (int kc = 0; kc < 4; ++kc) {
    bp[kc] = *(const f16x8*)(ws + WS_EP + (size_t)((kc * 8 + w) * 64 + lane) * 16);
    bn[kc] = *(const f16x8*)(ws + WS_EN + (size_t)((kc * 8 + w) * 64 + lane) * 16);
    bfr[kc] = *(const f16x8*)(ws + WS_BT + (size_t)((kc * 7 + (w % 7)) * 64 + lane) * 16);
  }
  const float bym = beta[yb * M_ + m];
  const float eta_v = ((const float*)(ws + WS_ETA))[b * M_ + m];

  __syncthreads();  // (1) ZAf ready

  // ---- B: base[8 p][112 c] = Z x beta^T (K=128); wave w<7 -> c-tile w ----
  if (w < 7) {
    f32x4 acc = {0.f, 0.f, 0.f, 0.f};
#pragma unroll
    for (int kc = 0; kc < 4; ++kc) {
      f16x8 a0 = *(const f16x8*)&ZAf[(kc * 64 + lane) * 8];
      acc = __builtin_amdgcn_mfma_f32_16x16x32_f16(a0, bfr[kc], acc, 0, 0, 0);
    }
    int col = w * 16 + l15;
    float b0v = (col < C_) ? beta0[col] : 0.f;
    if (lg < 2) {  // rows 0..7 valid
#pragma unroll
      for (int j = 0; j < 4; ++j) baseS[(lg * 4 + j) * 112 + col] = acc[j] + b0v;
    }
  }
  __syncthreads();  // (2) base ready

  // ---- C: softmax; wave w -> row p = w; write PtAf (+ zero pad row w+8) ----
  {
    int p = w;
    float v1 = baseS[p * 112 + lane];
    float v2 = (lane < 36) ? baseS[p * 112 + 64 + lane] : -1e30f;
    float mx = fmaxf(v1, v2);
#pragma unroll
    for (int off = 32; off > 0; off >>= 1) mx = fmaxf(mx, __shfl_xor(mx, off));
    float e1 = __expf(v1 - mx);
    float e2 = (lane < 36) ? __expf(v2 - mx) : 0.f;
    float sm = e1 + e2;
#pragma unroll
    for (int off = 32; off > 0; off >>= 1) sm += __shfl_xor(sm, off);
    float rd = 1.f / sm;
    float p1 = e1 * rd;
    float p2 = (lane < 36) ? e2 * rd : 0.f;
    {  // c = lane
      int c = lane, kc = c >> 5, lg2 = (c >> 3) & 3, ii = c & 7;
      PtAf[(kc * 64 + lg2 * 16 + p) * 8 + ii] = (f16)p1;
      PtAf[(kc * 64 + lg2 * 16 + p + 8) * 8 + ii] = (f16)0.f;
    }
    {  // c = lane + 64 (covers zero pad to c=127)
      int c = lane + 64, kc = c >> 5, lg2 = (c >> 3) & 3, ii = c & 7;
      PtAf[(kc * 64 + lg2 * 16 + p) * 8 + ii] = (f16)p2;
      PtAf[(kc * 64 + lg2 * 16 + p + 8) * 8 + ii] = (f16)0.f;
    }
    if (lane == yb) PybS[p] = p1;
    if (lane + 64 == yb) PybS[p] = p2;
  }
  __syncthreads();  // (3) PtAf, PybS ready

  // ---- D: den±[8 p][16 m] per wave (m-tile w), K=128 + epilogue ----
  {
    f32x4 pA = {0.f, 0.f, 0.f, 0.f}, nA = {0.f, 0.f, 0.f, 0.f};
#pragma unroll
    for (int kc = 0; kc < 4; ++kc) {
      f16x8 a0 = *(const f16x8*)&PtAf[(kc * 64 + lane) * 8];
      pA = __builtin_amdgcn_mfma_f32_16x16x32_f16(a0, bp[kc], pA, 0, 0, 0);
      nA = __builtin_amdgcn_mfma_f32_16x16x32_f16(a0, bn[kc], nA, 0, 0, 0);
    }
    float epy = __expf(2.f * bym), eny = 1.f / epy;
    float ome = 1.f - eta_v;
    float o = 0.f;
    int kcz = m >> 5, lgz = (m >> 3) & 3, iiz = m & 7;
    if (lg < 2) {  // rows p = lg*4+j < 8 valid
#pragma unroll
      for (int j = 0; j < 4; ++j) {
        int p = lg * 4 + j;
        float z = (float)ZAf[(kcz * 64 + lgz * 16 + p) * 8 + iiz];
        float pyb = PybS[p];
        o += (z > 0.f) ? fmaf(pyb, eta_v, (pyb * eny / nA[j]) * ome)
                       : fmaf(pyb * epy / pA[j], eta_v, pyb * ome);
      }
    }
    o += __shfl_xor(o, 16);
    o += __shfl_xor(o, 32);
    if (lane < 16) atomicAdd(&out[b * M_ + w * 16 + l15], o);
  }
}

extern "C" void kernel_launch(void* const* d_in, const int* in_sizes, int n_in,
                              void* d_out, int out_size, void* d_ws, size_t ws_size,
                              hipStream_t stream) {
  const float* x = (const float*)d_in[0];
  const int* y = (const int*)d_in[1];
  const float* Z = (const float*)d_in[2];
  const float* alpha0 = (const float*)d_in[3];
  const float* alpha = (const float*)d_in[4];
  const float* beta0 = (const float*)d_in[5];
  const float* beta = (const float*)d_in[6];
  float* out = (float*)d_out;
  char* ws = (char*)d_ws;

  k_pre<<<dim3(268), dim3(512), 0, stream>>>(x, alpha0, alpha, beta, ws, out);
  k_main<<<dim3(4, B_), dim3(512), 0, stream>>>(y, Z, beta0, beta, ws, out);
}

// Round 15
// 14.429 us; speedup vs baseline: 1.2967x; 1.0720x over previous
//
#include <hip/hip_runtime.h>
#include <math.h>

#define S_ 32
#define B_ 128
#define M_ 128
#define F_ 512
#define C_ 100
#define SB 16     // s-rows per k_main block

typedef _Float16 f16;
typedef _Float16 f16x8 __attribute__((ext_vector_type(8)));
typedef float f32x4 __attribute__((ext_vector_type(4)));

// ws layout (bytes):
//  BTf  @ 0     : 4 kc x 7 ct x 64 lane x 16B = 28672   beta frags   [B-op, phase B]
//  EPf  @ 28672 : 4 kc x 8 mt x 64 lane x 16B = 32768   exp(+2*beta) [B-op, phase D]
//  ENf  @ 61440 : 32768                                 exp(-2*beta)
//  etag @ 94208 : f32[128][128] = 65536
#define WS_BT  0
#define WS_EP  28672
#define WS_EN  61440
#define WS_ETA 94208

// ---- k_pre: blocks 0..127 -> eta row + zero out row; 128..139 -> tables ----
__global__ __launch_bounds__(512) void k_pre(
    const float* __restrict__ x, const float* __restrict__ alpha0,
    const float* __restrict__ alpha, const float* __restrict__ beta,
    char* __restrict__ ws, float* __restrict__ out) {
  const int bid = blockIdx.x;
  const int tid = threadIdx.x;
  __shared__ float betaS[C_ * M_];  // used by table blocks only
  if (bid < B_) {
    float* etag = (float*)(ws + WS_ETA);
    const int lane = tid & 63, w = tid >> 6, l15 = lane & 15, lg = lane >> 4;
    if (tid < M_) out[bid * M_ + tid] = 0.f;
    const float4* x4 = (const float4*)x;
    const float4* a4 = (const float4*)alpha;
    float4 xr[8];
#pragma unroll
    for (int r = 0; r < 8; ++r) xr[r] = x4[bid * 128 + r * 16 + l15];
#pragma unroll
    for (int j = 0; j < 4; ++j) {
      int m = w * 16 + j * 4 + lg;
      float acc = 0.f;
#pragma unroll
      for (int r = 0; r < 8; ++r) {
        float4 av = a4[(size_t)m * 128 + r * 16 + l15];
        float4 xv = xr[r];
        acc = fmaf(av.x, xv.x, acc); acc = fmaf(av.y, xv.y, acc);
        acc = fmaf(av.z, xv.z, acc); acc = fmaf(av.w, xv.w, acc);
      }
      acc += __shfl_xor(acc, 1);
      acc += __shfl_xor(acc, 2);
      acc += __shfl_xor(acc, 4);
      acc += __shfl_xor(acc, 8);
      if (l15 == 0) {
        float l = alpha0[m] + acc;
        etag[bid * 128 + m] = 1.f / (1.f + __expf(-l));
      }
    }
  } else {
    for (int i = tid; i < C_ * M_; i += 512) betaS[i] = beta[i];
    __syncthreads();
    const int ci = (bid - B_) * 512 + tid;  // 0..6143; active < 5888
    if (ci < 1792) {                        // BTf frag(kc,ct): beta[c][m-seg]
      int lane = ci & 63, t = ci >> 6;
      int ct = t % 7, kc = t / 7;
      int c = ct * 16 + (lane & 15);
      int m0 = kc * 32 + (lane >> 4) * 8;
      f16x8 v;
#pragma unroll
      for (int i = 0; i < 8; ++i)
        v[i] = (c < C_) ? (f16)betaS[c * M_ + m0 + i] : (f16)0.f;
      *(f16x8*)(ws + WS_BT + (size_t)ci * 16) = v;
    } else if (ci < 3840) {                 // EPf frag(kc,mt): exp(+2*beta[c-seg][m])
      int q = ci - 1792;
      int lane = q & 63, t = q >> 6;
      int m = (t & 7) * 16 + (lane & 15);
      int c0 = (t >> 3) * 32 + (lane >> 4) * 8;
      f16x8 v;
#pragma unroll
      for (int i = 0; i < 8; ++i) {
        int c = c0 + i;
        v[i] = (c < C_) ? (f16)__expf(2.f * betaS[c * M_ + m]) : (f16)0.f;
      }
      *(f16x8*)(ws + WS_EP + (size_t)q * 16) = v;
    } else if (ci < 5888) {                 // ENf
      int q = ci - 3840;
      int lane = q & 63, t = q >> 6;
      int m = (t & 7) * 16 + (lane & 15);
      int c0 = (t >> 3) * 32 + (lane >> 4) * 8;
      f16x8 v;
#pragma unroll
      for (int i = 0; i < 8; ++i) {
        int c = c0 + i;
        v[i] = (c < C_) ? (f16)__expf(-2.f * betaS[c * M_ + m]) : (f16)0.f;
      }
      *(f16x8*)(ws + WS_EN + (size_t)q * 16) = v;
    }
  }
}

// ---- k_main: grid (2 sh, 128 b), 512 thr = 8 waves; 16 s-rows per block ----
// LDS in fragment-blob layout (slot = frag*64+lane, 16B/slot): conflict-free b128.
__global__ __launch_bounds__(512) void k_main(
    const int* __restrict__ y, const float* __restrict__ Z,
    const float* __restrict__ beta0, const float* __restrict__ beta,
    const char* __restrict__ ws, float* __restrict__ out) {
  const int sh = blockIdx.x;   // 0,1
  const int b = blockIdx.y;    // 0..127
  const int tid = threadIdx.x;
  const int lane = tid & 63;
  const int w = tid >> 6;      // 0..7
  const int l15 = lane & 15;
  const int lg = lane >> 4;    // 0..3

  __shared__ __align__(16) f16 ZAf[256 * 8];    // 4 KB: Z frags (4 kc; rows = 16 p)
  __shared__ __align__(16) f16 PtAf[256 * 8];   // 4 KB: P frags (4 kc; rows = 16 p)
  __shared__ float baseS[SB * 112];             // 7 KB
  __shared__ float PybS[SB];

  const int yb = y[b];
  const int m = w * 16 + l15;  // this thread's m in phase D / epilogue (m-tile w)

  // ---- A: stage 16 Z rows into blob slots (tid<256: thread == slot) ----
  if (tid < 256) {
    int s = tid;
    int kcs = s >> 6, lgs = (s >> 4) & 3, p = s & 15;
    const float* zrow =
        Z + ((size_t)(sh * SB + p) * B_ + b) * M_ + kcs * 32 + lgs * 8;
    float4 u0 = *(const float4*)zrow;
    float4 u1 = *(const float4*)(zrow + 4);
    f16x8 hv = {(f16)u0.x, (f16)u0.y, (f16)u0.z, (f16)u0.w,
                (f16)u1.x, (f16)u1.y, (f16)u1.z, (f16)u1.w};
    *(f16x8*)&ZAf[s * 8] = hv;
  }

  // Issue-early: all ws fragments + epilogue scalars (hide under staging/B/C)
  f16x8 bfr[4], bp[4], bn[4];
#pragma unroll
  for (int kc = 0; kc < 4; ++kc) {
    bp[kc] = *(const f16x8*)(ws + WS_EP + (size_t)((kc * 8 + w) * 64 + lane) * 16);
    bn[kc] = *(const f16x8*)(ws + WS_EN + (size_t)((kc * 8 + w) * 64 + lane) * 16);
    bfr[kc] = *(const f16x8*)(ws + WS_BT + (size_t)((kc * 7 + (w % 7)) * 64 + lane) * 16);
  }
  const float bym = beta[yb * M_ + m];
  const float eta_v = ((const float*)(ws + WS_ETA))[b * M_ + m];
  const int colB = w * 16 + l15;
  const float b0v = (w < 7 && colB < C_) ? beta0[colB] : 0.f;

  __syncthreads();  // (1) ZAf ready

  // ---- B: base[16 p][112 c] = Z x beta^T (K=128); wave w<7 -> c-tile w ----
  if (w < 7) {
    f32x4 acc = {0.f, 0.f, 0.f, 0.f};
#pragma unroll
    for (int kc = 0; kc < 4; ++kc) {
      f16x8 a0 = *(const f16x8*)&ZAf[(kc * 64 + lane) * 8];
      acc = __builtin_amdgcn_mfma_f32_16x16x32_f16(a0, bfr[kc], acc, 0, 0, 0);
    }
#pragma unroll
    for (int j = 0; j < 4; ++j) baseS[(lg * 4 + j) * 112 + colB] = acc[j] + b0v;
  }
  __syncthreads();  // (2) base ready

  // ---- C: softmax; wave w -> rows p = 2w, 2w+1 -> PtAf blob slots ----
  {
#pragma unroll
    for (int k = 0; k < 2; ++k) {
      int p = w * 2 + k;
      float v1 = baseS[p * 112 + lane];
      float v2 = (lane < 36) ? baseS[p * 112 + 64 + lane] : -1e30f;
      float mx = fmaxf(v1, v2);
#pragma unroll
      for (int off = 32; off > 0; off >>= 1) mx = fmaxf(mx, __shfl_xor(mx, off));
      float e1 = __expf(v1 - mx);
      float e2 = (lane < 36) ? __expf(v2 - mx) : 0.f;
      float sm = e1 + e2;
#pragma unroll
      for (int off = 32; off > 0; off >>= 1) sm += __shfl_xor(sm, off);
      float rd = 1.f / sm;
      float p1 = e1 * rd;
      float p2 = (lane < 36) ? e2 * rd : 0.f;
      {  // c = lane
        int c = lane, kc = c >> 5, lg2 = (c >> 3) & 3, ii = c & 7;
        PtAf[(kc * 64 + lg2 * 16 + p) * 8 + ii] = (f16)p1;
      }
      {  // c = lane + 64 (covers zero pad to c=127)
        int c = lane + 64, kc = c >> 5, lg2 = (c >> 3) & 3, ii = c & 7;
        PtAf[(kc * 64 + lg2 * 16 + p) * 8 + ii] = (f16)p2;
      }
      if (lane == yb) PybS[p] = p1;
      if (lane + 64 == yb) PybS[p] = p2;
    }
  }
  __syncthreads();  // (3) PtAf, PybS ready

  // ---- D: den±[16 p][16 m] per wave (m-tile w), K=128 + epilogue ----
  {
    f32x4 pA = {0.f, 0.f, 0.f, 0.f}, nA = {0.f, 0.f, 0.f, 0.f};
#pragma unroll
    for (int kc = 0; kc < 4; ++kc) {
      f16x8 a0 = *(const f16x8*)&PtAf[(kc * 64 + lane) * 8];
      pA = __builtin_amdgcn_mfma_f32_16x16x32_f16(a0, bp[kc], pA, 0, 0, 0);
      nA = __builtin_amdgcn_mfma_f32_16x16x32_f16(a0, bn[kc], nA, 0, 0, 0);
    }
    float epy = __expf(2.f * bym), eny = 1.f / epy;
    float ome = 1.f - eta_v;
    float o = 0.f;
    int kcz = m >> 5, lgz = (m >> 3) & 3, iiz = m & 7;
#pragma unroll
    for (int j = 0; j < 4; ++j) {
      int p = lg * 4 + j;
      float z = (float)ZAf[(kcz * 64 + lgz * 16 + p) * 8 + iiz];
      float pyb = PybS[p];
      o += (z > 0.f) ? fmaf(pyb, eta_v, (pyb * eny / nA[j]) * ome)
                     : fmaf(pyb * epy / pA[j], eta_v, pyb * ome);
    }
    o += __shfl_xor(o, 16);
    o += __shfl_xor(o, 32);
    if (lane < 16) atomicAdd(&out[b * M_ + w * 16 + l15], o);
  }
}

extern "C" void kernel_launch(void* const* d_in, const int* in_sizes, int n_in,
                              void* d_out, int out_size, void* d_ws, size_t ws_size,
                              hipStream_t stream) {
  const float* x = (const float*)d_in[0];
  const int* y = (const int*)d_in[1];
  const float* Z = (const float*)d_in[2];
  const float* alpha0 = (const float*)d_in[3];
  const float* alpha = (const float*)d_in[4];
  const float* beta0 = (const float*)d_in[5];
  const float* beta = (const float*)d_in[6];
  float* out = (float*)d_out;
  char* ws = (char*)d_ws;

  k_pre<<<dim3(B_ + 12), dim3(512), 0, stream>>>(x, alpha0, alpha, beta, ws, out);
  k_main<<<dim3(2, B_), dim3(512), 0, stream>>>(y, Z, beta0, beta, ws, out);
}